// Round 8
// baseline (134.536 us; speedup 1.0000x reference)
//
#include <hip/hip_runtime.h>

#define NQ 8
#define BINS 256
#define D 128
#define RPB 16            // rows per block
#define THREADS 256       // 4 waves; grid = 512 -> 2 blocks/CU
#define RSTRIDE 132       // prep staging stride
#define FREG 520          // shorts per frag region (512 + 8 pad)

typedef short s8v __attribute__((ext_vector_type(8)));   // 8 bf16 in 4 VGPRs
typedef float f4v __attribute__((ext_vector_type(4)));   // MFMA accumulator

static __device__ __forceinline__ unsigned short bf16_rtne(float x) {
    unsigned u = __float_as_uint(x);
    unsigned r = (u + 0x7fffu + ((u >> 16) & 1u)) >> 16;
    return (unsigned short)r;
}
static __device__ __forceinline__ float bf16_to_f(unsigned short h) {
    return __uint_as_float(((unsigned)h) << 16);
}
struct Split3 { short h, m, l; };
static __device__ __forceinline__ Split3 split3(float x) {
    Split3 s;
    unsigned short hb = bf16_rtne(x);
    float r1 = x - bf16_to_f(hb);
    unsigned short mb = bf16_rtne(r1);
    unsigned short lb = bf16_rtne(r1 - bf16_to_f(mb));
    s.h = (short)hb; s.m = (short)mb; s.l = (short)lb;
    return s;
}
static __device__ __forceinline__ unsigned long long shfl_xor_u64(unsigned long long v, int mask) {
    int lo = (int)(unsigned)(v & 0xffffffffull);
    int hi = (int)(unsigned)(v >> 32);
    lo = __shfl_xor(lo, mask, 64);
    hi = __shfl_xor(hi, mask, 64);
    return ((unsigned long long)(unsigned)hi << 32) | (unsigned)lo;
}
static __device__ __forceinline__ unsigned long long u64min(unsigned long long a, unsigned long long b) {
    return a < b ? a : b;
}

// ---- prep: codebooks fp32 -> bf16 3-way split (swizzled [L][kchunk][bin][8]) + ||c||^2 ----
__global__ __launch_bounds__(256) void rvq_prep(
    const float* __restrict__ cb, short* __restrict__ cb_hi,
    short* __restrict__ cb_mid, short* __restrict__ cb_lo,
    float* __restrict__ c2)
{
    __shared__ float st[16 * RSTRIDE];
    const int L = blockIdx.x >> 4;     // level
    const int o = blockIdx.x & 15;     // 16-bin group
    const int t = threadIdx.x;

    const float4* src = (const float4*)(cb + ((size_t)L * BINS + o * 16) * D);
    #pragma unroll
    for (int i = 0; i < 2; ++i) {
        int f4 = i * 256 + t;
        int row = f4 >> 5, c4 = f4 & 31;
        float4 v = src[f4];
        float* d = &st[row * RSTRIDE + c4 * 4];
        d[0] = v.x; d[1] = v.y; d[2] = v.z; d[3] = v.w;
    }
    __syncthreads();

    const int bin = t >> 4;
    const int kc  = t & 15;
    const float* p = &st[bin * RSTRIDE + kc * 8];
    s8v h8, m8, l8;
    float s = 0.f;
    #pragma unroll
    for (int j = 0; j < 8; ++j) {
        float x = p[j];
        Split3 sp = split3(x);
        h8[j] = sp.h; m8[j] = sp.m; l8[j] = sp.l;
        s = fmaf(x, x, s);
    }
    int idx = (L * 16 + kc) * BINS + (o * 16 + bin);
    ((s8v*)cb_hi)[idx]  = h8;
    ((s8v*)cb_mid)[idx] = m8;
    ((s8v*)cb_lo)[idx]  = l8;
    s += __shfl_xor(s, 1, 64);
    s += __shfl_xor(s, 2, 64);
    s += __shfl_xor(s, 4, 64);
    s += __shfl_xor(s, 8, 64);
    if (kc == 0) c2[L * BINS + o * 16 + bin] = s;
}

// frag store: thread owns (row rr_ 0..15, kchunk g8 0..15)
static __device__ __forceinline__ void frag_store(
    const float* rres, short* ah, short* am, short* al, int rr_, int g8)
{
    s8v h8, m8, l8;
    #pragma unroll
    for (int j = 0; j < 8; ++j) {
        Split3 sp = split3(rres[j]);
        h8[j] = sp.h; m8[j] = sp.m; l8[j] = sp.l;
    }
    int q = g8 & 3;
    int reg = g8 >> 2;                             // ks region 0..3
    int idx16 = q * 16 + ((rr_ + 4 * q) & 15);
    int off = reg * FREG + idx16 * 8;
    *(s8v*)&ah[off] = h8;
    *(s8v*)&am[off] = m8;
    *(s8v*)&al[off] = l8;
}

// ---- main: 16 rows/block, 4 waves, nt=4 x 16 bins, B double-buffered ----
__global__ __launch_bounds__(THREADS, 2) void rvq_kernel(
    const float* __restrict__ hidden,     // [N, D]
    const float* __restrict__ cb_f32,     // [NQ, BINS, D]
    const short* __restrict__ cb_hi,
    const short* __restrict__ cb_mid,
    const short* __restrict__ cb_lo,
    const float* __restrict__ c2p,        // [NQ, BINS]
    float* __restrict__ out_codes,        // [NQ, N] as float
    float* __restrict__ out_quant,        // [N, D]
    int N)
{
    __shared__ short ah[4 * FREG];
    __shared__ short am[4 * FREG];
    __shared__ short al[4 * FREG];
    __shared__ unsigned long long redw[RPB][4];

    const int t = threadIdx.x;
    const int w = t >> 6;                 // wave 0..3
    const int l = t & 63;
    const int quad = l >> 4;
    const int m = l & 15;
    const int row0 = blockIdx.x * RPB;
    const int woff = w * 64;              // this wave's 64-bin window
    const int rr_ = t >> 4;               // owned row 0..15
    const int g8 = t & 15;                // owned k-chunk

    float rres[8];
    {
        const float4* hp = (const float4*)(hidden + (size_t)(row0 + rr_) * D + g8 * 8);
        float4 v0 = hp[0], v1 = hp[1];
        rres[0] = v0.x; rres[1] = v0.y; rres[2] = v0.z; rres[3] = v0.w;
        rres[4] = v1.x; rres[5] = v1.y; rres[6] = v1.z; rres[7] = v1.w;
    }
    frag_store(rres, ah, am, al, rr_, g8);

    const s8v* bhp = (const s8v*)cb_hi;
    const s8v* bmp = (const s8v*)cb_mid;
    const s8v* blp = (const s8v*)cb_lo;

    for (int level = 0; level < NQ; ++level) {
        s8v bh[2][4], bm[2][4], bl[2][4];
        float c2v[2];

        // prefetch nt=0 into buffer 0 (pre-barrier: latency absorbed by drain)
        {
            int bin = woff + m;
            c2v[0] = c2p[level * BINS + bin];
            #pragma unroll
            for (int ks = 0; ks < 4; ++ks) {
                int idx = (level * 16 + ks * 4 + quad) * BINS + bin;
                bh[0][ks] = bhp[idx];
                bm[0][ks] = bmp[idx];
                bl[0][ks] = blp[idx];
            }
        }
        __syncthreads();   // frag writes visible

        // A fragments (swizzled, conflict-free)
        s8v afh[4], afm[4], afl[4];
        #pragma unroll
        for (int ks = 0; ks < 4; ++ks) {
            int idx16 = quad * 16 + ((m + 4 * quad) & 15);
            int off = ks * FREG + idx16 * 8;
            afh[ks] = *(const s8v*)&ah[off];
            afm[ks] = *(const s8v*)&am[off];
            afl[ks] = *(const s8v*)&al[off];
        }

        unsigned long long best[4] = {~0ull, ~0ull, ~0ull, ~0ull};

        #pragma unroll
        for (int nt = 0; nt < 4; ++nt) {
            const int cur = nt & 1;
            if (nt < 3) {   // prefetch nt+1 into the other buffer
                int bin = woff + (nt + 1) * 16 + m;
                c2v[1 - cur] = c2p[level * BINS + bin];
                #pragma unroll
                for (int ks = 0; ks < 4; ++ks) {
                    int idx = (level * 16 + ks * 4 + quad) * BINS + bin;
                    bh[1 - cur][ks] = bhp[idx];
                    bm[1 - cur][ks] = bmp[idx];
                    bl[1 - cur][ks] = blp[idx];
                }
            }
            const int bin = woff + nt * 16 + m;
            f4v a0 = {0.f, 0.f, 0.f, 0.f};   // hh
            f4v a1 = {0.f, 0.f, 0.f, 0.f};   // hm + mh
            f4v a2 = {0.f, 0.f, 0.f, 0.f};   // mm + hl + lh
            #pragma unroll
            for (int ks = 0; ks < 4; ++ks) {
                a0 = __builtin_amdgcn_mfma_f32_16x16x32_bf16(afh[ks], bh[cur][ks], a0, 0, 0, 0);
                a1 = __builtin_amdgcn_mfma_f32_16x16x32_bf16(afh[ks], bm[cur][ks], a1, 0, 0, 0);
                a1 = __builtin_amdgcn_mfma_f32_16x16x32_bf16(afm[ks], bh[cur][ks], a1, 0, 0, 0);
                a2 = __builtin_amdgcn_mfma_f32_16x16x32_bf16(afm[ks], bm[cur][ks], a2, 0, 0, 0);
                a2 = __builtin_amdgcn_mfma_f32_16x16x32_bf16(afh[ks], bl[cur][ks], a2, 0, 0, 0);
                a2 = __builtin_amdgcn_mfma_f32_16x16x32_bf16(afl[ks], bh[cur][ks], a2, 0, 0, 0);
            }
            #pragma unroll
            for (int i = 0; i < 4; ++i) {
                float dot = a0[i] + (a1[i] + a2[i]);      // small terms first
                float k = fmaf(-2.f, dot, c2v[cur]);
                unsigned u = __float_as_uint(k);
                u = (u & 0x80000000u) ? ~u : (u | 0x80000000u);
                unsigned long long key = ((unsigned long long)u << 32) | (unsigned)bin;
                best[i] = u64min(best[i], key);
            }
        }

        // argmin within 16-lane groups; stash per-wave
        #pragma unroll
        for (int i = 0; i < 4; ++i) {
            unsigned long long p = best[i];
            p = u64min(p, shfl_xor_u64(p, 1));
            p = u64min(p, shfl_xor_u64(p, 2));
            p = u64min(p, shfl_xor_u64(p, 4));
            p = u64min(p, shfl_xor_u64(p, 8));
            if (m == 0) redw[quad * 4 + i][w] = p;
        }
        __syncthreads();

        // every thread reduces its own row's 4 wave-results (broadcast reads)
        unsigned long long mn = redw[rr_][0];
        #pragma unroll
        for (int j = 1; j < 4; ++j) mn = u64min(mn, redw[rr_][j]);
        const int wb = (int)(mn & 0xffffffffull);
        if (g8 == 0)
            out_codes[(size_t)level * N + row0 + rr_] = (float)wb;

        // fp32 residual update in registers (elementwise, matches reference)
        {
            const float4* cp = (const float4*)(cb_f32 + ((size_t)level * BINS + wb) * D + g8 * 8);
            float4 c0 = cp[0], c1 = cp[1];
            rres[0] -= c0.x; rres[1] -= c0.y; rres[2] -= c0.z; rres[3] -= c0.w;
            rres[4] -= c1.x; rres[5] -= c1.y; rres[6] -= c1.z; rres[7] -= c1.w;
        }
        frag_store(rres, ah, am, al, rr_, g8);
    }

    // epilogue: quantized = hidden - residual
    {
        const float4* hp = (const float4*)(hidden + (size_t)(row0 + rr_) * D + g8 * 8);
        float4 v0 = hp[0], v1 = hp[1];
        float4 q0, q1;
        q0.x = v0.x - rres[0]; q0.y = v0.y - rres[1]; q0.z = v0.z - rres[2]; q0.w = v0.w - rres[3];
        q1.x = v1.x - rres[4]; q1.y = v1.y - rres[5]; q1.z = v1.z - rres[6]; q1.w = v1.w - rres[7];
        float4* op = (float4*)(out_quant + (size_t)(row0 + rr_) * D + g8 * 8);
        op[0] = q0; op[1] = q1;
    }
}

extern "C" void kernel_launch(void* const* d_in, const int* in_sizes, int n_in,
                              void* d_out, int out_size, void* d_ws, size_t ws_size,
                              hipStream_t stream) {
    const float* hidden    = (const float*)d_in[0];
    const float* codebooks = (const float*)d_in[1];
    float* out = (float*)d_out;
    const int N = in_sizes[0] / D;                 // 8192
    float* out_codes = out;                        // [NQ, N]
    float* out_quant = out + (size_t)NQ * N;       // [N, D]

    char* ws = (char*)d_ws;
    short* cb_hi  = (short*)ws;                    // 512 KB
    short* cb_mid = (short*)(ws +  512 * 1024);    // 512 KB
    short* cb_lo  = (short*)(ws + 1024 * 1024);    // 512 KB
    float* c2     = (float*)(ws + 1536 * 1024);    // 8 KB

    rvq_prep<<<dim3(NQ * 16), 256, 0, stream>>>(codebooks, cb_hi, cb_mid, cb_lo, c2);
    rvq_kernel<<<dim3(N / RPB), THREADS, 0, stream>>>(
        hidden, codebooks, cb_hi, cb_mid, cb_lo, c2, out_codes, out_quant, N);
}